// Round 4
// baseline (261.915 us; speedup 1.0000x reference)
//
#include <hip/hip_runtime.h>
#include <math.h>
#include <type_traits>

#define CC 62
#define TT 1000
#define HH 14
#define NPAIR 105      // 14*15/2 upper-triangle pairs
#define NCHEB 20       // Chebyshev terms (degree 19), closed-form coefs
// log(x) on [0.25, 2.0]:  log(c + d*y), c=1.125, d=0.875, y in [-1,1]
// A = (c + sqrt(c^2-d^2))/2, r = -d/(2A);  log = logA - 2*sum_k (r^k/k) T_k(y)
#define LOG_A  (-0.08768183236702332f)
#define CH_R   (-0.47759225007251715f)

// ---- compile-time for: guarantees constant array indices (no scratch) ----
template <int N, typename F>
__device__ __forceinline__ void static_for(F&& f) {
    if constexpr (N > 0) {
        static_for<N - 1>(f);
        f(std::integral_constant<int, N - 1>{});
    }
}

constexpr int pair_i(int p) {
    int i = 0;
    while (p >= HH - i) { p -= HH - i; ++i; }
    return i;
}
constexpr int pair_j(int p) {
    int i = 0;
    while (p >= HH - i) { p -= HH - i; ++i; }
    return i + p;
}

// compute 4 rows (CB..CB+3) from BUF into z accumulators
#define COMPUTE4(BUF, CB)                                                  \
    static_for<4>([&](auto CI) {                                           \
        constexpr int ci = CI.value;                                       \
        const float* wr = w1 + ((CB) + ci) * HH;                           \
        const float4 xv = BUF[ci];                                         \
        static_for<HH>([&](auto H_) {                                      \
            constexpr int h = H_.value;                                    \
            const float w = wr[h];      /* wave-uniform -> scalar load */  \
            z0[h] = fmaf(w, xv.x, z0[h]);                                  \
            z1[h] = fmaf(w, xv.y, z1[h]);                                  \
            z2[h] = fmaf(w, xv.z, z2[h]);                                  \
            z3[h] = fmaf(w, xv.w, z3[h]);                                  \
        });                                                                \
    });

// issue 4 row loads (CB..CB+3) into BUF
#define LOAD4(BUF, CB)                                                     \
    static_for<4>([&](auto CI) {                                           \
        BUF[CI.value] = *(const float4*)(xt + (size_t)((CB) + CI.value) * TT); \
    });

__global__ __launch_bounds__(256, 4) void spdnet_fused(
    const float* __restrict__ x,
    const float* __restrict__ w1,
    const float* __restrict__ w2,
    const float* __restrict__ w3,
    const float* __restrict__ fcw,
    const float* __restrict__ fcb,
    float* __restrict__ out)
{
    const int b    = blockIdx.x;
    const int tid  = threadIdx.x;
    const int lane = tid & 63;
    const int wv   = tid >> 6;

    __shared__ float coef[NCHEB];
    __shared__ float Qm[196];          // w2 @ w3
    __shared__ float Sm[196];          // s1
    __shared__ float Ym[196];          // scaled Clenshaw argument
    __shared__ float Bufs[3][196];     // Clenshaw b_k buffers
    __shared__ float Lm[196];          // logm(s1)
    __shared__ float Tm[196];          // L @ Q
    __shared__ float Fm[196];          // Q^T L Q
    __shared__ float wpart[4][NPAIR + HH];
    __shared__ float lpart[4][2];

    // ---- closed-form Chebyshev coefficients of log on [0.25, 2] ----
    if (tid == 0) {
        coef[0] = 2.0f * LOG_A;            // Clenshaw adds 0.5*coef[0]
        float rk = 1.0f;
        for (int k = 1; k < NCHEB; ++k) {
            rk *= CH_R;
            coef[k] = -2.0f * rk / (float)k;
        }
    }
    // ---- Qm = w2 @ w3 (small, L2-cached) ----
    if (tid < 196) {
        int i = tid / 14, j = tid % 14;
        float acc = 0.f;
        #pragma unroll
        for (int k = 0; k < 14; ++k) acc = fmaf(w2[i*14 + k], w3[k*14 + j], acc);
        Qm[tid] = acc;
    }

    // ---- main streaming pass: each thread owns 4 consecutive t (float4) ----
    // 2-deep register pipeline: while computing one 4-row group, the next
    // 4-row group's loads stay in flight (compiler waits vmcnt(4), not 0).
    float z0[HH], z1[HH], z2[HH], z3[HH];
    static_for<HH>([&](auto H_) {
        constexpr int h = H_.value;
        z0[h] = 0.f; z1[h] = 0.f; z2[h] = 0.f; z3[h] = 0.f;
    });

    const float* xb = x + (size_t)b * (CC * TT);
    const int t = tid * 4;

    if (t < TT) {                       // tid < 250 active
        const float* xt = xb + t;
        float4 bufA[4], bufB[4];
        LOAD4(bufA, 0)
        LOAD4(bufB, 4)
        #pragma unroll 1
        for (int cb = 0; cb < 48; cb += 8) {
            COMPUTE4(bufA, cb)
            LOAD4(bufA, cb + 8)
            COMPUTE4(bufB, cb + 4)
            LOAD4(bufB, cb + 12)
        }
        // bufA = rows 48..51, bufB = rows 52..55
        COMPUTE4(bufA, 48)
        LOAD4(bufA, 56)
        COMPUTE4(bufB, 52)
        const float4 e0 = *(const float4*)(xt + (size_t)60 * TT);
        const float4 e1 = *(const float4*)(xt + (size_t)61 * TT);
        COMPUTE4(bufA, 56)
        static_for<HH>([&](auto H_) {
            constexpr int h = H_.value;
            const float wa = w1[60 * HH + h];
            const float wb = w1[61 * HH + h];
            z0[h] = fmaf(wa, e0.x, z0[h]);  z0[h] = fmaf(wb, e1.x, z0[h]);
            z1[h] = fmaf(wa, e0.y, z1[h]);  z1[h] = fmaf(wb, e1.y, z1[h]);
            z2[h] = fmaf(wa, e0.z, z2[h]);  z2[h] = fmaf(wb, e1.z, z2[h]);
            z3[h] = fmaf(wa, e0.w, z3[h]);  z3[h] = fmaf(wb, e1.w, z3[h]);
        });
    }

    // ---- Gram pairs computed on-the-fly and immediately reduced ----
    static_for<NPAIR>([&](auto P) {
        constexpr int p = P.value;
        constexpr int i = pair_i(p);
        constexpr int j = pair_j(p);
        float v = z0[i] * z0[j];
        v = fmaf(z1[i], z1[j], v);
        v = fmaf(z2[i], z2[j], v);
        v = fmaf(z3[i], z3[j], v);
        v += __shfl_down(v, 32, 64);
        v += __shfl_down(v, 16, 64);
        v += __shfl_down(v,  8, 64);
        v += __shfl_down(v,  4, 64);
        v += __shfl_down(v,  2, 64);
        v += __shfl_down(v,  1, 64);
        if (lane == 0) wpart[wv][p] = v;
    });
    static_for<HH>([&](auto H_) {
        constexpr int h = H_.value;
        float v = z0[h] + z1[h] + z2[h] + z3[h];
        v += __shfl_down(v, 32, 64);
        v += __shfl_down(v, 16, 64);
        v += __shfl_down(v,  8, 64);
        v += __shfl_down(v,  4, 64);
        v += __shfl_down(v,  2, 64);
        v += __shfl_down(v,  1, 64);
        if (lane == 0) wpart[wv][NPAIR + h] = v;
    });
    __syncthreads();

    if (tid < NPAIR) {
        float g = wpart[0][tid] + wpart[1][tid] + wpart[2][tid] + wpart[3][tid];
        int i = 0, rem = tid;
        while (rem >= HH - i) { rem -= HH - i; ++i; }
        int j = i + rem;
        float mi = wpart[0][NPAIR+i] + wpart[1][NPAIR+i] + wpart[2][NPAIR+i] + wpart[3][NPAIR+i];
        float mj = wpart[0][NPAIR+j] + wpart[1][NPAIR+j] + wpart[2][NPAIR+j] + wpart[3][NPAIR+j];
        float s = g * (1.0f / TT) - mi * mj * (1.0f / ((float)TT * (float)TT));
        Sm[i*14 + j] = s;
        Sm[j*14 + i] = s;
    }
    __syncthreads();

    // ---- Y = (2 S - (a+b) I) / (b-a); init Clenshaw buffers ----
    if (tid < 196) {
        int i = tid / 14, j = tid % 14;
        float d = (i == j) ? 1.f : 0.f;
        Ym[tid] = (2.0f * Sm[tid] - 2.25f * d) * (1.0f / 1.75f);
        Bufs[0][tid] = 0.f;
        Bufs[1][tid] = 0.f;
    }
    __syncthreads();

    // ---- Clenshaw: logm(s1) = 0.5 c0 I + sum c_k T_k(Y) ----
    int ib1 = 0, ib2 = 1, ibn = 2;
    for (int k = NCHEB - 1; k >= 1; --k) {
        if (tid < 196) {
            int i = tid / 14, j = tid % 14;
            float acc = 0.f;
            #pragma unroll
            for (int kk = 0; kk < 14; ++kk)
                acc = fmaf(Ym[i*14 + kk], Bufs[ib1][kk*14 + j], acc);
            Bufs[ibn][tid] = 2.0f * acc - Bufs[ib2][tid] + ((i == j) ? coef[k] : 0.f);
        }
        __syncthreads();
        int t0 = ib2; ib2 = ib1; ib1 = ibn; ibn = t0;
    }
    if (tid < 196) {
        int i = tid / 14, j = tid % 14;
        float acc = 0.f;
        #pragma unroll
        for (int kk = 0; kk < 14; ++kk)
            acc = fmaf(Ym[i*14 + kk], Bufs[ib1][kk*14 + j], acc);
        Lm[tid] = acc - Bufs[ib2][tid] + ((i == j) ? 0.5f * coef[0] : 0.f);
    }
    __syncthreads();

    // ---- F = Q^T L Q ----
    if (tid < 196) {
        int i = tid / 14, j = tid % 14;
        float acc = 0.f;
        #pragma unroll
        for (int kk = 0; kk < 14; ++kk)
            acc = fmaf(Lm[i*14 + kk], Qm[kk*14 + j], acc);
        Tm[tid] = acc;
    }
    __syncthreads();
    if (tid < 196) {
        int i = tid / 14, j = tid % 14;
        float acc = 0.f;
        #pragma unroll
        for (int kk = 0; kk < 14; ++kk)
            acc = fmaf(Qm[kk*14 + i], Tm[kk*14 + j], acc);
        Fm[tid] = acc;
    }
    __syncthreads();

    // ---- logits + sigmoid ----
    float v0 = 0.f, v1 = 0.f;
    if (tid < 196) {
        float f = Fm[tid];
        v0 = f * fcw[tid];
        v1 = f * fcw[196 + tid];
    }
    v0 += __shfl_down(v0, 32, 64);  v1 += __shfl_down(v1, 32, 64);
    v0 += __shfl_down(v0, 16, 64);  v1 += __shfl_down(v1, 16, 64);
    v0 += __shfl_down(v0,  8, 64);  v1 += __shfl_down(v1,  8, 64);
    v0 += __shfl_down(v0,  4, 64);  v1 += __shfl_down(v1,  4, 64);
    v0 += __shfl_down(v0,  2, 64);  v1 += __shfl_down(v1,  2, 64);
    v0 += __shfl_down(v0,  1, 64);  v1 += __shfl_down(v1,  1, 64);
    if (lane == 0) { lpart[wv][0] = v0; lpart[wv][1] = v1; }
    __syncthreads();
    if (tid == 0) {
        float l0 = lpart[0][0] + lpart[1][0] + lpart[2][0] + lpart[3][0] + fcb[0];
        float l1 = lpart[0][1] + lpart[1][1] + lpart[2][1] + lpart[3][1] + fcb[1];
        out[b*2 + 0] = 1.0f / (1.0f + expf(-l0));
        out[b*2 + 1] = 1.0f / (1.0f + expf(-l1));
    }
}

extern "C" void kernel_launch(void* const* d_in, const int* in_sizes, int n_in,
                              void* d_out, int out_size, void* d_ws, size_t ws_size,
                              hipStream_t stream) {
    const float* x   = (const float*)d_in[0];
    const float* w1  = (const float*)d_in[1];
    const float* w2  = (const float*)d_in[2];
    const float* w3  = (const float*)d_in[3];
    const float* fcw = (const float*)d_in[4];
    const float* fcb = (const float*)d_in[5];
    float* out = (float*)d_out;
    int B = in_sizes[0] / (CC * TT);
    spdnet_fused<<<B, 256, 0, stream>>>(x, w1, w2, w3, fcw, fcb, out);
}

// Round 5
// 170.308 us; speedup vs baseline: 1.5379x; 1.5379x over previous
//
#include <hip/hip_runtime.h>
#include <math.h>
#include <type_traits>

#define CC 62
#define TT 1000
#define HH 14
#define NPAIR 105      // 14*15/2 upper-triangle pairs
#define NCHEB 20       // Chebyshev terms (degree 19), closed-form coefs
// log(x) on [0.25, 2.0]:  log(c + d*y), c=1.125, d=0.875, y in [-1,1]
// A = (c + sqrt(c^2-d^2))/2, r = -d/(2A);  log = logA - 2*sum_k (r^k/k) T_k(y)
#define LOG_A  (-0.08768183236702332f)
#define CH_R   (-0.47759225007251715f)

// ---- compile-time for: guarantees constant array indices (no scratch) ----
template <int N, typename F>
__device__ __forceinline__ void static_for(F&& f) {
    if constexpr (N > 0) {
        static_for<N - 1>(f);
        f(std::integral_constant<int, N - 1>{});
    }
}

constexpr int pair_i(int p) {
    int i = 0;
    while (p >= HH - i) { p -= HH - i; ++i; }
    return i;
}
constexpr int pair_j(int p) {
    int i = 0;
    while (p >= HH - i) { p -= HH - i; ++i; }
    return i + p;
}

__global__ __launch_bounds__(256, 4) void spdnet_fused(
    const float* __restrict__ x,
    const float* __restrict__ w1,
    const float* __restrict__ w2,
    const float* __restrict__ w3,
    const float* __restrict__ fcw,
    const float* __restrict__ fcb,
    float* __restrict__ out)
{
    const int b    = blockIdx.x;
    const int tid  = threadIdx.x;
    const int lane = tid & 63;
    const int wv   = tid >> 6;

    __shared__ float coef[NCHEB];
    __shared__ float Qm[196];          // w2 @ w3
    __shared__ float Sm[196];          // s1
    __shared__ float Ym[196];          // scaled Clenshaw argument
    __shared__ float Bufs[3][196];     // Clenshaw b_k buffers
    __shared__ float Lm[196];          // logm(s1)
    __shared__ float Tm[196];          // L @ Q
    __shared__ float Fm[196];          // Q^T L Q
    __shared__ float wpart[4][NPAIR + HH];
    __shared__ float lpart[4][2];

    // ---- closed-form Chebyshev coefficients of log on [0.25, 2] ----
    if (tid == 0) {
        coef[0] = 2.0f * LOG_A;            // Clenshaw adds 0.5*coef[0]
        float rk = 1.0f;
        for (int k = 1; k < NCHEB; ++k) {
            rk *= CH_R;
            coef[k] = -2.0f * rk / (float)k;
        }
    }
    // ---- Qm = w2 @ w3 (small, L2-cached) ----
    if (tid < 196) {
        int i = tid / 14, j = tid % 14;
        float acc = 0.f;
        #pragma unroll
        for (int k = 0; k < 14; ++k) acc = fmaf(w2[i*14 + k], w3[k*14 + j], acc);
        Qm[tid] = acc;
    }

    // ---- main streaming pass ----
    // 16 groups of rows: g<15 -> rows 4g..4g+3, g==15 -> rows 60,61.
    // 3-buffer rotation, loads issued 2 groups ahead of their compute:
    // during every FMA burst, 8 float4 loads (8KB/wave) stay in flight.
    float z0[HH], z1[HH], z2[HH], z3[HH];
    static_for<HH>([&](auto H_) {
        constexpr int h = H_.value;
        z0[h] = 0.f; z1[h] = 0.f; z2[h] = 0.f; z3[h] = 0.f;
    });

    const float* xb = x + (size_t)b * (CC * TT);
    const int t = tid * 4;

    if (t < TT) {                       // tid < 250 active
        const float* xt = xb + t;
        float4 buf[3][4];               // all indices compile-time -> registers

        auto loadg = [&](auto Gc) {
            constexpr int g  = Gc.value;
            constexpr int bs = g % 3;
            constexpr int nr = (g == 15) ? 2 : 4;
            static_for<nr>([&](auto CI) {
                constexpr int ci = CI.value;
                buf[bs][ci] = *(const float4*)(xt + (size_t)(4 * g + ci) * TT);
            });
        };
        auto computeg = [&](auto Gc) {
            constexpr int g  = Gc.value;
            constexpr int bs = g % 3;
            constexpr int nr = (g == 15) ? 2 : 4;
            static_for<nr>([&](auto CI) {
                constexpr int ci = CI.value;
                const float* wr = w1 + (4 * g + ci) * HH;
                const float4 xv = buf[bs][ci];
                static_for<HH>([&](auto H_) {
                    constexpr int h = H_.value;
                    const float w = wr[h];    // wave-uniform -> scalar load
                    z0[h] = fmaf(w, xv.x, z0[h]);
                    z1[h] = fmaf(w, xv.y, z1[h]);
                    z2[h] = fmaf(w, xv.z, z2[h]);
                    z3[h] = fmaf(w, xv.w, z3[h]);
                });
            });
        };

        loadg(std::integral_constant<int, 0>{});
        loadg(std::integral_constant<int, 1>{});
        static_for<16>([&](auto Gc) {
            constexpr int g = Gc.value;
            if constexpr (g + 2 <= 15)
                loadg(std::integral_constant<int, g + 2>{});
            computeg(Gc);
        });
    }

    // ---- Gram pairs computed on-the-fly and immediately reduced ----
    static_for<NPAIR>([&](auto P) {
        constexpr int p = P.value;
        constexpr int i = pair_i(p);
        constexpr int j = pair_j(p);
        float v = z0[i] * z0[j];
        v = fmaf(z1[i], z1[j], v);
        v = fmaf(z2[i], z2[j], v);
        v = fmaf(z3[i], z3[j], v);
        v += __shfl_down(v, 32, 64);
        v += __shfl_down(v, 16, 64);
        v += __shfl_down(v,  8, 64);
        v += __shfl_down(v,  4, 64);
        v += __shfl_down(v,  2, 64);
        v += __shfl_down(v,  1, 64);
        if (lane == 0) wpart[wv][p] = v;
    });
    static_for<HH>([&](auto H_) {
        constexpr int h = H_.value;
        float v = z0[h] + z1[h] + z2[h] + z3[h];
        v += __shfl_down(v, 32, 64);
        v += __shfl_down(v, 16, 64);
        v += __shfl_down(v,  8, 64);
        v += __shfl_down(v,  4, 64);
        v += __shfl_down(v,  2, 64);
        v += __shfl_down(v,  1, 64);
        if (lane == 0) wpart[wv][NPAIR + h] = v;
    });
    __syncthreads();

    if (tid < NPAIR) {
        float g = wpart[0][tid] + wpart[1][tid] + wpart[2][tid] + wpart[3][tid];
        int i = 0, rem = tid;
        while (rem >= HH - i) { rem -= HH - i; ++i; }
        int j = i + rem;
        float mi = wpart[0][NPAIR+i] + wpart[1][NPAIR+i] + wpart[2][NPAIR+i] + wpart[3][NPAIR+i];
        float mj = wpart[0][NPAIR+j] + wpart[1][NPAIR+j] + wpart[2][NPAIR+j] + wpart[3][NPAIR+j];
        float s = g * (1.0f / TT) - mi * mj * (1.0f / ((float)TT * (float)TT));
        Sm[i*14 + j] = s;
        Sm[j*14 + i] = s;
    }
    __syncthreads();

    // ---- Y = (2 S - (a+b) I) / (b-a); init Clenshaw buffers ----
    if (tid < 196) {
        int i = tid / 14, j = tid % 14;
        float d = (i == j) ? 1.f : 0.f;
        Ym[tid] = (2.0f * Sm[tid] - 2.25f * d) * (1.0f / 1.75f);
        Bufs[0][tid] = 0.f;
        Bufs[1][tid] = 0.f;
    }
    __syncthreads();

    // ---- Clenshaw: logm(s1) = 0.5 c0 I + sum c_k T_k(Y) ----
    int ib1 = 0, ib2 = 1, ibn = 2;
    for (int k = NCHEB - 1; k >= 1; --k) {
        if (tid < 196) {
            int i = tid / 14, j = tid % 14;
            float acc = 0.f;
            #pragma unroll
            for (int kk = 0; kk < 14; ++kk)
                acc = fmaf(Ym[i*14 + kk], Bufs[ib1][kk*14 + j], acc);
            Bufs[ibn][tid] = 2.0f * acc - Bufs[ib2][tid] + ((i == j) ? coef[k] : 0.f);
        }
        __syncthreads();
        int t0 = ib2; ib2 = ib1; ib1 = ibn; ibn = t0;
    }
    if (tid < 196) {
        int i = tid / 14, j = tid % 14;
        float acc = 0.f;
        #pragma unroll
        for (int kk = 0; kk < 14; ++kk)
            acc = fmaf(Ym[i*14 + kk], Bufs[ib1][kk*14 + j], acc);
        Lm[tid] = acc - Bufs[ib2][tid] + ((i == j) ? 0.5f * coef[0] : 0.f);
    }
    __syncthreads();

    // ---- F = Q^T L Q ----
    if (tid < 196) {
        int i = tid / 14, j = tid % 14;
        float acc = 0.f;
        #pragma unroll
        for (int kk = 0; kk < 14; ++kk)
            acc = fmaf(Lm[i*14 + kk], Qm[kk*14 + j], acc);
        Tm[tid] = acc;
    }
    __syncthreads();
    if (tid < 196) {
        int i = tid / 14, j = tid % 14;
        float acc = 0.f;
        #pragma unroll
        for (int kk = 0; kk < 14; ++kk)
            acc = fmaf(Qm[kk*14 + i], Tm[kk*14 + j], acc);
        Fm[tid] = acc;
    }
    __syncthreads();

    // ---- logits + sigmoid ----
    float v0 = 0.f, v1 = 0.f;
    if (tid < 196) {
        float f = Fm[tid];
        v0 = f * fcw[tid];
        v1 = f * fcw[196 + tid];
    }
    v0 += __shfl_down(v0, 32, 64);  v1 += __shfl_down(v1, 32, 64);
    v0 += __shfl_down(v0, 16, 64);  v1 += __shfl_down(v1, 16, 64);
    v0 += __shfl_down(v0,  8, 64);  v1 += __shfl_down(v1,  8, 64);
    v0 += __shfl_down(v0,  4, 64);  v1 += __shfl_down(v1,  4, 64);
    v0 += __shfl_down(v0,  2, 64);  v1 += __shfl_down(v1,  2, 64);
    v0 += __shfl_down(v0,  1, 64);  v1 += __shfl_down(v1,  1, 64);
    if (lane == 0) { lpart[wv][0] = v0; lpart[wv][1] = v1; }
    __syncthreads();
    if (tid == 0) {
        float l0 = lpart[0][0] + lpart[1][0] + lpart[2][0] + lpart[3][0] + fcb[0];
        float l1 = lpart[0][1] + lpart[1][1] + lpart[2][1] + lpart[3][1] + fcb[1];
        out[b*2 + 0] = 1.0f / (1.0f + expf(-l0));
        out[b*2 + 1] = 1.0f / (1.0f + expf(-l1));
    }
}

extern "C" void kernel_launch(void* const* d_in, const int* in_sizes, int n_in,
                              void* d_out, int out_size, void* d_ws, size_t ws_size,
                              hipStream_t stream) {
    const float* x   = (const float*)d_in[0];
    const float* w1  = (const float*)d_in[1];
    const float* w2  = (const float*)d_in[2];
    const float* w3  = (const float*)d_in[3];
    const float* fcw = (const float*)d_in[4];
    const float* fcb = (const float*)d_in[5];
    float* out = (float*)d_out;
    int B = in_sizes[0] / (CC * TT);
    spdnet_fused<<<B, 256, 0, stream>>>(x, w1, w2, w3, fcw, fcb, out);
}